// Round 2
// baseline (193.174 us; speedup 1.0000x reference)
//
#include <hip/hip_runtime.h>
#include <hip/hip_bf16.h>

#define BB 16
#define NN 16384
#define DD 128
#define CC 32
#define CHUNKS 128
#define ROWS_PER_BLOCK (NN / CHUNKS)   // 128

// ---------------- Kernel 1: segment sums + counts ----------------
// Grid: (CHUNKS, BB) = 2048 blocks, block 256 -> 8 blocks/CU, ~100% occupancy.
// LDS accumulator lsum[c][j], j = permuted d-index (d = sub*4+k stored at k*32+sub)
// so each ds_add wave hits banks 0..31 exactly twice (free 2-way). The permutation
// is cluster-uniform and the gram sums over d, so it cancels downstream.
__global__ __launch_bounds__(256) void seg_sum_kernel(
    const float* __restrict__ x, const int* __restrict__ ids,
    float* __restrict__ gsums, float* __restrict__ gcounts) {
  __shared__ float lsum[CC * DD];        // 16 KB
  __shared__ float lcnt[CC];
  __shared__ int   lcid[ROWS_PER_BLOCK]; // 512 B

  const int tid  = threadIdx.x;
  const int b    = blockIdx.y;
  const int row0 = blockIdx.x * ROWS_PER_BLOCK;
  const int* __restrict__ idrow = ids + (size_t)b * NN;

  for (int i = tid; i < CC * DD; i += 256) lsum[i] = 0.f;
  if (tid < CC) lcnt[tid] = 0.f;
  if (tid < ROWS_PER_BLOCK) lcid[tid] = idrow[row0 + tid];
  __syncthreads();

  // counts straight from staged ids (32 clusters -> light contention)
  if (tid < ROWS_PER_BLOCK) atomicAdd(&lcnt[lcid[tid]], 1.f);

  const int sub  = tid & 31;   // float4 index within row
  const int rloc = tid >> 5;   // 0..7 -> 8 rows per iteration

  const float4* __restrict__ x4 =
      reinterpret_cast<const float4*>(x + (size_t)b * NN * DD);

#pragma unroll 4
  for (int i = 0; i < ROWS_PER_BLOCK / 8; ++i) {
    const int r = rloc + i * 8;
    float4 v = x4[(size_t)(row0 + r) * 32 + sub];
    int cid  = lcid[r];
    float* dst = &lsum[cid * DD + sub];
    atomicAdd(dst +  0, v.x);
    atomicAdd(dst + 32, v.y);
    atomicAdd(dst + 64, v.z);
    atomicAdd(dst + 96, v.w);
  }
  __syncthreads();

  float* __restrict__ gs = gsums + (size_t)b * CC * DD;
  for (int i = tid; i < CC * DD; i += 256) atomicAdd(&gs[i], lsum[i]);
  if (tid < CC) atomicAdd(&gcounts[b * CC + tid], lcnt[tid]);
}

// ---------------- Kernel 2: means -> gram -> triu sum -> mean ----------------
#define MSTR 129   // 129 % 32 == 1 -> conflict-free pair-dot reads
__global__ __launch_bounds__(256) void finish_kernel(
    const float* __restrict__ gsums, const float* __restrict__ gcounts,
    float* __restrict__ out) {
  __shared__ float mean[CC * MSTR];  // 16.5 KB
  __shared__ float cnt[CC];
  __shared__ float red[256];

  const int b = blockIdx.x;
  const int tid = threadIdx.x;

  if (tid < CC) cnt[tid] = gcounts[b * CC + tid];
  __syncthreads();

  for (int i = tid; i < CC * DD; i += 256) {
    int c = i >> 7;
    int d = i & 127;
    mean[c * MSTR + d] = gsums[(size_t)b * CC * DD + i] / fmaxf(cnt[c], 1.f);
  }
  __syncthreads();

  float acc = 0.f;
  for (int p = tid; p < (CC * (CC - 1)) / 2; p += 256) {
    int c = 0, rem = p;
    while (rem >= (CC - 1 - c)) { rem -= (CC - 1 - c); ++c; }
    int e = c + 1 + rem;
    const float* mc = &mean[c * MSTR];
    const float* me = &mean[e * MSTR];
    float dot = 0.f;
#pragma unroll 8
    for (int d = 0; d < DD; ++d) dot += mc[d] * me[d];
    acc += fabsf(dot);
  }

  red[tid] = acc;
  __syncthreads();
  for (int s = 128; s > 0; s >>= 1) {
    if (tid < s) red[tid] += red[tid + s];
    __syncthreads();
  }

  if (tid == 0) {
    float valid = 0.f;
    for (int c = 0; c < CC; ++c) valid += (cnt[c] > 0.f) ? 1.f : 0.f;
    float denom = (valid > 1.f) ? valid * (valid - 1.f) * 0.5f : 1.f;
    atomicAdd(out, red[0] / denom * (1.0f / BB));
  }
}

extern "C" void kernel_launch(void* const* d_in, const int* in_sizes, int n_in,
                              void* d_out, int out_size, void* d_ws, size_t ws_size,
                              hipStream_t stream) {
  const float* x   = (const float*)d_in[0];
  const int*   ids = (const int*)d_in[1];
  float* out = (float*)d_out;

  float* gsums   = (float*)d_ws;                       // BB*CC*DD floats = 256 KB
  float* gcounts = gsums + (size_t)BB * CC * DD;       // BB*CC floats

  const size_t ws_bytes = ((size_t)BB * CC * DD + (size_t)BB * CC) * sizeof(float);
  hipMemsetAsync(d_ws, 0, ws_bytes, stream);
  hipMemsetAsync(d_out, 0, sizeof(float), stream);

  dim3 grid1(CHUNKS, BB);
  seg_sum_kernel<<<grid1, 256, 0, stream>>>(x, ids, gsums, gcounts);
  finish_kernel<<<BB, 256, 0, stream>>>(gsums, gcounts, out);
}

// Round 3
// 59.160 us; speedup vs baseline: 3.2653x; 3.2653x over previous
//
#include <hip/hip_runtime.h>
#include <hip/hip_bf16.h>

#define BB 16
#define NN 16384
#define DD 128
#define CC 32
#define CHUNKS 32
#define ROWS_PER_BLOCK (NN / CHUNKS)   // 512
#define ROWS_PER_WAVE  (ROWS_PER_BLOCK / 4)  // 128

// ---------------- Kernel 1: segment sums + counts (register accumulation) ----
// Grid: (CHUNKS, BB) = 512 blocks, 256 thr (4 waves). Each wave owns 128
// contiguous rows; lane l owns d = {2l, 2l+1}. Cluster id is wave-uniform per
// row -> readfirstlane + scalar switch: exactly 2 VALU adds per row per lane,
// ZERO atomics in the hot loop. Flush: plain LDS writes + 4-way reduce +
// one global atomicAdd per element (2M total, proven cheap in R1/R2).
#define CASE_ADD(k) case k: accx[k] += vv.x; accy[k] += vv.y; break;

__global__ __launch_bounds__(256) void seg_sum_kernel(
    const float* __restrict__ x, const int* __restrict__ ids,
    float* __restrict__ gsums, float* __restrict__ gcounts) {
  __shared__ float lsum[4 * CC * DD];     // 64 KB: per-wave partials
  __shared__ float lcnt[CC];
  __shared__ int   lcid[ROWS_PER_BLOCK];  // 2 KB

  const int tid  = threadIdx.x;
  const int b    = blockIdx.y;
  const int row0 = blockIdx.x * ROWS_PER_BLOCK;
  const int lane = tid & 63;
  const int w    = tid >> 6;              // wave 0..3
  const int* __restrict__ idrow = ids + (size_t)b * NN;

  // stage ids + counts (512 LDS atomics per block — negligible)
  if (tid < CC) lcnt[tid] = 0.f;
  lcid[tid]       = idrow[row0 + tid];
  lcid[tid + 256] = idrow[row0 + tid + 256];
  __syncthreads();
  atomicAdd(&lcnt[lcid[tid]], 1.f);
  atomicAdd(&lcnt[lcid[tid + 256]], 1.f);

  float accx[32], accy[32];
#pragma unroll
  for (int c = 0; c < CC; ++c) { accx[c] = 0.f; accy[c] = 0.f; }

  const float2* __restrict__ x2 =
      reinterpret_cast<const float2*>(x + (size_t)b * NN * DD);
  const int wbase = w * ROWS_PER_WAVE;

  for (int g = 0; g < ROWS_PER_WAVE / 8; ++g) {   // 16 groups of 8 rows
    float2 v[8];
    int cid[8];
#pragma unroll
    for (int k = 0; k < 8; ++k) {
      const int rl = wbase + g * 8 + k;
      v[k]   = x2[(size_t)(row0 + rl) * 64 + lane];
      cid[k] = lcid[rl];
    }
#pragma unroll
    for (int k = 0; k < 8; ++k) {
      const int c = __builtin_amdgcn_readfirstlane(cid[k]);
      const float2 vv = v[k];
      switch (c) {
        CASE_ADD(0)  CASE_ADD(1)  CASE_ADD(2)  CASE_ADD(3)
        CASE_ADD(4)  CASE_ADD(5)  CASE_ADD(6)  CASE_ADD(7)
        CASE_ADD(8)  CASE_ADD(9)  CASE_ADD(10) CASE_ADD(11)
        CASE_ADD(12) CASE_ADD(13) CASE_ADD(14) CASE_ADD(15)
        CASE_ADD(16) CASE_ADD(17) CASE_ADD(18) CASE_ADD(19)
        CASE_ADD(20) CASE_ADD(21) CASE_ADD(22) CASE_ADD(23)
        CASE_ADD(24) CASE_ADD(25) CASE_ADD(26) CASE_ADD(27)
        CASE_ADD(28) CASE_ADD(29) CASE_ADD(30) CASE_ADD(31)
        default: break;
      }
    }
  }

  // per-wave partial -> LDS (plain writes, no atomics; each wave covers
  // its full 32x128 slab so no zero-init needed)
  float* ws = &lsum[w * CC * DD];
#pragma unroll
  for (int c = 0; c < CC; ++c) {
    *reinterpret_cast<float2*>(&ws[c * DD + 2 * lane]) =
        make_float2(accx[c], accy[c]);
  }
  __syncthreads();

  // 4-way reduce + global atomic flush (CC*DD = 4096 elems, 16 iters)
  float* __restrict__ gs = gsums + (size_t)b * CC * DD;
  for (int i = tid; i < CC * DD; i += 256) {
    float s = lsum[i] + lsum[CC * DD + i] + lsum[2 * CC * DD + i] +
              lsum[3 * CC * DD + i];
    atomicAdd(&gs[i], s);
  }
  if (tid < CC) atomicAdd(&gcounts[b * CC + tid], lcnt[tid]);
}

// ---------------- Kernel 2: means -> gram -> triu sum -> mean ----------------
#define MSTR 129   // 129 % 32 == 1 -> conflict-free pair-dot reads
__global__ __launch_bounds__(256) void finish_kernel(
    const float* __restrict__ gsums, const float* __restrict__ gcounts,
    float* __restrict__ out) {
  __shared__ float mean[CC * MSTR];  // 16.5 KB
  __shared__ float cnt[CC];
  __shared__ float red[256];

  const int b = blockIdx.x;
  const int tid = threadIdx.x;

  if (tid < CC) cnt[tid] = gcounts[b * CC + tid];
  __syncthreads();

  for (int i = tid; i < CC * DD; i += 256) {
    int c = i >> 7;
    int d = i & 127;
    mean[c * MSTR + d] = gsums[(size_t)b * CC * DD + i] / fmaxf(cnt[c], 1.f);
  }
  __syncthreads();

  float acc = 0.f;
  for (int p = tid; p < (CC * (CC - 1)) / 2; p += 256) {
    int c = 0, rem = p;
    while (rem >= (CC - 1 - c)) { rem -= (CC - 1 - c); ++c; }
    int e = c + 1 + rem;
    const float* mc = &mean[c * MSTR];
    const float* me = &mean[e * MSTR];
    float dot = 0.f;
#pragma unroll 8
    for (int d = 0; d < DD; ++d) dot += mc[d] * me[d];
    acc += fabsf(dot);
  }

  red[tid] = acc;
  __syncthreads();
  for (int s = 128; s > 0; s >>= 1) {
    if (tid < s) red[tid] += red[tid + s];
    __syncthreads();
  }

  if (tid == 0) {
    float valid = 0.f;
    for (int c = 0; c < CC; ++c) valid += (cnt[c] > 0.f) ? 1.f : 0.f;
    float denom = (valid > 1.f) ? valid * (valid - 1.f) * 0.5f : 1.f;
    atomicAdd(out, red[0] / denom * (1.0f / BB));
  }
}

extern "C" void kernel_launch(void* const* d_in, const int* in_sizes, int n_in,
                              void* d_out, int out_size, void* d_ws, size_t ws_size,
                              hipStream_t stream) {
  const float* x   = (const float*)d_in[0];
  const int*   ids = (const int*)d_in[1];
  float* out = (float*)d_out;

  float* gsums   = (float*)d_ws;                       // BB*CC*DD floats = 256 KB
  float* gcounts = gsums + (size_t)BB * CC * DD;       // BB*CC floats

  const size_t ws_bytes = ((size_t)BB * CC * DD + (size_t)BB * CC) * sizeof(float);
  hipMemsetAsync(d_ws, 0, ws_bytes, stream);
  hipMemsetAsync(d_out, 0, sizeof(float), stream);

  dim3 grid1(CHUNKS, BB);
  seg_sum_kernel<<<grid1, 256, 0, stream>>>(x, ids, gsums, gcounts);
  finish_kernel<<<BB, 256, 0, stream>>>(gsums, gcounts, out);
}

// Round 4
// 45.916 us; speedup vs baseline: 4.2071x; 1.2884x over previous
//
#include <hip/hip_runtime.h>
#include <hip/hip_bf16.h>

#define BB 16
#define NN 16384
#define DD 128
#define CC 32
#define CHUNKS 32
#define ROWS_PER_BLOCK (NN / CHUNKS)        // 512
#define ROWS_PER_WAVE  (ROWS_PER_BLOCK / 4) // 128

// ---------------- Kernel 1: segment sums + counts (branchless LDS RMW) ------
// Grid: (CHUNKS, BB) = 512 blocks, 256 thr (4 waves). Each wave owns 128
// contiguous rows and a private 16 KB LDS slab. Per row: lane l holds
// d = {2l, 2l+1} (float2, coalesced 512 B/row) and does a plain
// ds_read_b64 + 2*v_add + ds_write_b64 at slab[cid*128 + 2l].
// - no branches (R3's scalar switch serialized the per-CU branch unit)
// - no atomics (R1/R2's LDS atomic RMW ran at ~3.2 cyc/lane-add/CU)
// - within a wave, lanes hit distinct addresses; DS ops complete in order
//   per wave, so row-to-row RMW on a repeated cid is safe; slabs are
//   per-wave so there are no cross-wave races.
__global__ __launch_bounds__(256) void seg_sum_kernel(
    const float* __restrict__ x, const int* __restrict__ ids,
    float* __restrict__ gsums, float* __restrict__ gcounts) {
  __shared__ float lsum[4][CC * DD];      // 64 KB: per-wave slabs
  __shared__ float lcnt[CC];
  __shared__ int   lcid[ROWS_PER_BLOCK];  // 2 KB

  const int tid  = threadIdx.x;
  const int b    = blockIdx.y;
  const int row0 = blockIdx.x * ROWS_PER_BLOCK;
  const int lane = tid & 63;
  const int w    = tid >> 6;              // wave 0..3
  const int* __restrict__ idrow = ids + (size_t)b * NN;

  // stage ids + zero own slab + counts
  if (tid < CC) lcnt[tid] = 0.f;
  lcid[tid]       = idrow[row0 + tid];
  lcid[tid + 256] = idrow[row0 + tid + 256];
  {
    const float4 z4 = make_float4(0.f, 0.f, 0.f, 0.f);
#pragma unroll
    for (int i = 0; i < 16; ++i)
      *reinterpret_cast<float4*>(&lsum[w][(i * 64 + lane) * 4]) = z4;
  }
  __syncthreads();
  atomicAdd(&lcnt[lcid[tid]], 1.f);
  atomicAdd(&lcnt[lcid[tid + 256]], 1.f);

  const float2* __restrict__ x2 =
      reinterpret_cast<const float2*>(x + (size_t)b * NN * DD);
  const int wbase = w * ROWS_PER_WAVE;
  float* const slab = &lsum[w][0];

  for (int g = 0; g < ROWS_PER_WAVE / 8; ++g) {   // 16 groups of 8 rows
    float2 v[8];
    int cid[8];
#pragma unroll
    for (int k = 0; k < 8; ++k) {
      const int rl = wbase + g * 8 + k;
      v[k]   = x2[(size_t)(row0 + rl) * 64 + lane];
      cid[k] = lcid[rl];
    }
#pragma unroll
    for (int k = 0; k < 8; ++k) {
      float2* p = reinterpret_cast<float2*>(&slab[cid[k] * DD + 2 * lane]);
      float2 old = *p;
      *p = make_float2(old.x + v[k].x, old.y + v[k].y);
    }
  }
  __syncthreads();

  // 4-way reduce across wave slabs + global atomic flush (2M atomics total)
  float* __restrict__ gs = gsums + (size_t)b * CC * DD;
  for (int i = tid; i < CC * DD; i += 256) {
    float s = lsum[0][i] + lsum[1][i] + lsum[2][i] + lsum[3][i];
    atomicAdd(&gs[i], s);
  }
  if (tid < CC) atomicAdd(&gcounts[b * CC + tid], lcnt[tid]);
}

// ---------------- Kernel 2: means -> gram -> triu sum -> mean ----------------
#define MSTR 129   // 129 % 32 == 1 -> conflict-free pair-dot reads
__global__ __launch_bounds__(256) void finish_kernel(
    const float* __restrict__ gsums, const float* __restrict__ gcounts,
    float* __restrict__ out) {
  __shared__ float mean[CC * MSTR];  // 16.5 KB
  __shared__ float cnt[CC];
  __shared__ float red[256];

  const int b = blockIdx.x;
  const int tid = threadIdx.x;

  if (tid < CC) cnt[tid] = gcounts[b * CC + tid];
  __syncthreads();

  for (int i = tid; i < CC * DD; i += 256) {
    int c = i >> 7;
    int d = i & 127;
    mean[c * MSTR + d] = gsums[(size_t)b * CC * DD + i] / fmaxf(cnt[c], 1.f);
  }
  __syncthreads();

  float acc = 0.f;
  for (int p = tid; p < (CC * (CC - 1)) / 2; p += 256) {
    int c = 0, rem = p;
    while (rem >= (CC - 1 - c)) { rem -= (CC - 1 - c); ++c; }
    int e = c + 1 + rem;
    const float* mc = &mean[c * MSTR];
    const float* me = &mean[e * MSTR];
    float dot = 0.f;
#pragma unroll 8
    for (int d = 0; d < DD; ++d) dot += mc[d] * me[d];
    acc += fabsf(dot);
  }

  red[tid] = acc;
  __syncthreads();
  for (int s = 128; s > 0; s >>= 1) {
    if (tid < s) red[tid] += red[tid + s];
    __syncthreads();
  }

  if (tid == 0) {
    float valid = 0.f;
    for (int c = 0; c < CC; ++c) valid += (cnt[c] > 0.f) ? 1.f : 0.f;
    float denom = (valid > 1.f) ? valid * (valid - 1.f) * 0.5f : 1.f;
    atomicAdd(out, red[0] / denom * (1.0f / BB));
  }
}

extern "C" void kernel_launch(void* const* d_in, const int* in_sizes, int n_in,
                              void* d_out, int out_size, void* d_ws, size_t ws_size,
                              hipStream_t stream) {
  const float* x   = (const float*)d_in[0];
  const int*   ids = (const int*)d_in[1];
  float* out = (float*)d_out;

  float* gsums   = (float*)d_ws;                       // BB*CC*DD floats = 256 KB
  float* gcounts = gsums + (size_t)BB * CC * DD;       // BB*CC floats

  const size_t ws_bytes = ((size_t)BB * CC * DD + (size_t)BB * CC) * sizeof(float);
  hipMemsetAsync(d_ws, 0, ws_bytes, stream);
  hipMemsetAsync(d_out, 0, sizeof(float), stream);

  dim3 grid1(CHUNKS, BB);
  seg_sum_kernel<<<grid1, 256, 0, stream>>>(x, ids, gsums, gcounts);
  finish_kernel<<<BB, 256, 0, stream>>>(gsums, gcounts, out);
}

// Round 5
// 44.375 us; speedup vs baseline: 4.3532x; 1.0347x over previous
//
#include <hip/hip_runtime.h>
#include <hip/hip_bf16.h>

#define BB 16
#define NN 16384
#define DD 128
#define CC 32
#define CHUNKS 32
#define ROWS_PER_BLOCK (NN / CHUNKS)        // 512
#define ROWS_PER_WAVE  (ROWS_PER_BLOCK / 4) // 128

// ---------------- Kernel 1: segment sums + counts (branchless LDS RMW) ------
// Grid: (CHUNKS, BB) = 512 blocks, 256 thr (4 waves), 2 blocks/CU (132 KB LDS).
// Each wave owns 128 contiguous rows + a private 16 KB slab. Per row: lane l
// holds d={2l,2l+1}; plain ds_read_b64 + 2 adds + ds_write_b64 (no atomics,
// no branches). R5 change: double-buffered prefetch — group g+1's 8 loads are
// issued before group g's RMW, so counted vmcnt keeps 4 KB/wave in flight.
__global__ __launch_bounds__(256) void seg_sum_kernel(
    const float* __restrict__ x, const int* __restrict__ ids,
    float* __restrict__ gsums, float* __restrict__ gcounts) {
  __shared__ float lsum[4][CC * DD];      // 64 KB: per-wave slabs
  __shared__ float lcnt[CC];
  __shared__ int   lcid[ROWS_PER_BLOCK];  // 2 KB

  const int tid  = threadIdx.x;
  const int b    = blockIdx.y;
  const int row0 = blockIdx.x * ROWS_PER_BLOCK;
  const int lane = tid & 63;
  const int w    = tid >> 6;              // wave 0..3
  const int* __restrict__ idrow = ids + (size_t)b * NN;

  if (tid < CC) lcnt[tid] = 0.f;
  lcid[tid]       = idrow[row0 + tid];
  lcid[tid + 256] = idrow[row0 + tid + 256];
  {
    const float4 z4 = make_float4(0.f, 0.f, 0.f, 0.f);
#pragma unroll
    for (int i = 0; i < 16; ++i)
      *reinterpret_cast<float4*>(&lsum[w][(i * 64 + lane) * 4]) = z4;
  }
  __syncthreads();
  atomicAdd(&lcnt[lcid[tid]], 1.f);
  atomicAdd(&lcnt[lcid[tid + 256]], 1.f);

  const float2* __restrict__ x2 =
      reinterpret_cast<const float2*>(x + (size_t)b * NN * DD);
  const int wbase = w * ROWS_PER_WAVE;
  float* const slab = &lsum[w][0];

  float2 vA[8], vB[8];
  int cA[8], cB[8];

#define LOADG(V, C, g)                                                     \
  {                                                                        \
    _Pragma("unroll") for (int k = 0; k < 8; ++k) {                        \
      const int rl = wbase + (g) * 8 + k;                                  \
      V[k] = x2[(size_t)(row0 + rl) * 64 + lane];                          \
      C[k] = lcid[rl];                                                     \
    }                                                                      \
  }
#define RMWG(V, C)                                                         \
  {                                                                        \
    _Pragma("unroll") for (int k = 0; k < 8; ++k) {                        \
      float2* p = reinterpret_cast<float2*>(&slab[C[k] * DD + 2 * lane]);  \
      float2 old = *p;                                                     \
      *p = make_float2(old.x + V[k].x, old.y + V[k].y);                    \
    }                                                                      \
  }

  LOADG(vA, cA, 0)
#pragma unroll
  for (int i = 0; i < 7; ++i) {           // pairs (0,1)..(12,13), A holds even
    LOADG(vB, cB, 2 * i + 1)
    RMWG(vA, cA)
    LOADG(vA, cA, 2 * i + 2)
    RMWG(vB, cB)
  }
  LOADG(vB, cB, 15)
  RMWG(vA, cA)                            // group 14
  RMWG(vB, cB)                            // group 15
#undef LOADG
#undef RMWG
  __syncthreads();

  // 4-way reduce across wave slabs + global atomic flush (2M atomics total)
  float* __restrict__ gs = gsums + (size_t)b * CC * DD;
  for (int i = tid; i < CC * DD; i += 256) {
    float s = lsum[0][i] + lsum[1][i] + lsum[2][i] + lsum[3][i];
    atomicAdd(&gs[i], s);
  }
  if (tid < CC) atomicAdd(&gcounts[b * CC + tid], lcnt[tid]);
}

// ---------------- Kernel 2: means -> gram -> triu sum -> mean ----------------
// 512 thr: each thread computes <=1 pair with float4 LDS reads (MSTR=132 keeps
// rows 16B-aligned: 132*4 % 16 == 0).
#define MSTR 132
__global__ __launch_bounds__(512) void finish_kernel(
    const float* __restrict__ gsums, const float* __restrict__ gcounts,
    float* __restrict__ out) {
  __shared__ float mean[CC * MSTR];  // 16.9 KB
  __shared__ float cnt[CC];
  __shared__ float red[512];

  const int b = blockIdx.x;
  const int tid = threadIdx.x;

  if (tid < CC) cnt[tid] = gcounts[b * CC + tid];
  __syncthreads();

  for (int i = tid; i < CC * DD; i += 512) {
    int c = i >> 7;
    int d = i & 127;
    mean[c * MSTR + d] = gsums[(size_t)b * CC * DD + i] / fmaxf(cnt[c], 1.f);
  }
  __syncthreads();

  float acc = 0.f;
  if (tid < (CC * (CC - 1)) / 2) {
    int c = 0, rem = tid;
    while (rem >= (CC - 1 - c)) { rem -= (CC - 1 - c); ++c; }
    int e = c + 1 + rem;
    const float4* mc = reinterpret_cast<const float4*>(&mean[c * MSTR]);
    const float4* me = reinterpret_cast<const float4*>(&mean[e * MSTR]);
    float dot = 0.f;
#pragma unroll 8
    for (int j = 0; j < DD / 4; ++j) {
      float4 a = mc[j], bb = me[j];
      dot += a.x * bb.x + a.y * bb.y + a.z * bb.z + a.w * bb.w;
    }
    acc = fabsf(dot);
  }

  red[tid] = acc;
  __syncthreads();
  for (int s = 256; s > 0; s >>= 1) {
    if (tid < s) red[tid] += red[tid + s];
    __syncthreads();
  }

  if (tid == 0) {
    float valid = 0.f;
    for (int c = 0; c < CC; ++c) valid += (cnt[c] > 0.f) ? 1.f : 0.f;
    float denom = (valid > 1.f) ? valid * (valid - 1.f) * 0.5f : 1.f;
    atomicAdd(out, red[0] / denom * (1.0f / BB));
  }
}

extern "C" void kernel_launch(void* const* d_in, const int* in_sizes, int n_in,
                              void* d_out, int out_size, void* d_ws, size_t ws_size,
                              hipStream_t stream) {
  const float* x   = (const float*)d_in[0];
  const int*   ids = (const int*)d_in[1];
  float* out = (float*)d_out;

  float* gsums   = (float*)d_ws;                       // BB*CC*DD floats = 256 KB
  float* gcounts = gsums + (size_t)BB * CC * DD;       // BB*CC floats

  const size_t ws_bytes = ((size_t)BB * CC * DD + (size_t)BB * CC) * sizeof(float);
  hipMemsetAsync(d_ws, 0, ws_bytes, stream);
  hipMemsetAsync(d_out, 0, sizeof(float), stream);

  dim3 grid1(CHUNKS, BB);
  seg_sum_kernel<<<grid1, 256, 0, stream>>>(x, ids, gsums, gcounts);
  finish_kernel<<<BB, 512, 0, stream>>>(gsums, gcounts, out);
}

// Round 6
// 40.895 us; speedup vs baseline: 4.7236x; 1.0851x over previous
//
#include <hip/hip_runtime.h>
#include <hip/hip_bf16.h>

#define BB 16
#define NN 16384
#define DD 128
#define CC 32
#define CHUNKS 32
#define NBLK (BB * CHUNKS)                  // 512
#define ROWS_PER_BLOCK (NN / CHUNKS)        // 512
#define ROWS_PER_WAVE  (ROWS_PER_BLOCK / 4) // 128

// ---- PATH A workspace layout (floats) ----
#define P_SUMS 0                                   // NBLK*4096
#define P_CNTS ((size_t)NBLK * CC * DD)            // NBLK*32
#define R_SUMS (P_CNTS + (size_t)NBLK * CC)        // BB*4096
#define R_CNTS (R_SUMS + (size_t)BB * CC * DD)     // BB*32
#define LOSSP  (R_CNTS + (size_t)BB * CC)          // BB
#define WS_A_FLOATS (LOSSP + BB)

// ---------------- Kernel 1: segment sums + counts (branchless LDS RMW) ------
// 512 blocks, 4 waves; per-wave private 16 KB slab; lane l owns d={2l,2l+1}.
// Hot loop: plain ds_read_b64 + 2 adds + ds_write_b64, 16 loads in flight.
// mode==1: plain-store 16 KB partial to slot (PATH A). mode==0: atomicAdd (B).
__global__ __launch_bounds__(256) void seg_sum_kernel(
    const float* __restrict__ x, const int* __restrict__ ids,
    float* __restrict__ outsums, float* __restrict__ outcnts, int mode) {
  __shared__ float lsum[4][CC * DD];      // 64 KB
  __shared__ float lcnt[CC];
  __shared__ int   lcid[ROWS_PER_BLOCK];  // 2 KB

  const int tid  = threadIdx.x;
  const int b    = blockIdx.y;
  const int row0 = blockIdx.x * ROWS_PER_BLOCK;
  const int lane = tid & 63;
  const int w    = tid >> 6;
  const int slot = b * CHUNKS + blockIdx.x;
  const int* __restrict__ idrow = ids + (size_t)b * NN;

  if (tid < CC) lcnt[tid] = 0.f;
  lcid[tid]       = idrow[row0 + tid];
  lcid[tid + 256] = idrow[row0 + tid + 256];
  {
    const float4 z4 = make_float4(0.f, 0.f, 0.f, 0.f);
#pragma unroll
    for (int i = 0; i < 16; ++i)
      *reinterpret_cast<float4*>(&lsum[w][(i * 64 + lane) * 4]) = z4;
  }
  __syncthreads();
  atomicAdd(&lcnt[lcid[tid]], 1.f);
  atomicAdd(&lcnt[lcid[tid + 256]], 1.f);

  const float2* __restrict__ x2 =
      reinterpret_cast<const float2*>(x + (size_t)b * NN * DD);
  const int wbase = w * ROWS_PER_WAVE;
  float* const slab = &lsum[w][0];

  float2 vA[16], vB[16];
  int cA[16], cB[16];

#define LOADG(V, C, g)                                                     \
  {                                                                        \
    _Pragma("unroll") for (int k = 0; k < 16; ++k) {                       \
      const int rl = wbase + (g) * 16 + k;                                 \
      V[k] = x2[(size_t)(row0 + rl) * 64 + lane];                          \
      C[k] = lcid[rl];                                                     \
    }                                                                      \
  }
#define RMWG(V, C)                                                         \
  {                                                                        \
    _Pragma("unroll") for (int k = 0; k < 16; ++k) {                       \
      float2* p = reinterpret_cast<float2*>(&slab[C[k] * DD + 2 * lane]);  \
      float2 old = *p;                                                     \
      *p = make_float2(old.x + V[k].x, old.y + V[k].y);                    \
    }                                                                      \
  }

  LOADG(vA, cA, 0)                         // 8 groups of 16 rows
#pragma unroll
  for (int i = 0; i < 3; ++i) {
    LOADG(vB, cB, 2 * i + 1)
    RMWG(vA, cA)
    LOADG(vA, cA, 2 * i + 2)
    RMWG(vB, cB)
  }
  LOADG(vB, cB, 7)
  RMWG(vA, cA)
  RMWG(vB, cB)
#undef LOADG
#undef RMWG
  __syncthreads();

  if (mode) {  // PATH A: plain stores to private slot
    float* __restrict__ ps = outsums + (size_t)slot * CC * DD;
#pragma unroll
    for (int it = 0; it < 4; ++it) {
      const int i = (it * 256 + tid) * 4;
      float4 s0 = *reinterpret_cast<const float4*>(&lsum[0][i]);
      float4 s1 = *reinterpret_cast<const float4*>(&lsum[1][i]);
      float4 s2 = *reinterpret_cast<const float4*>(&lsum[2][i]);
      float4 s3 = *reinterpret_cast<const float4*>(&lsum[3][i]);
      float4 r = make_float4(s0.x + s1.x + s2.x + s3.x, s0.y + s1.y + s2.y + s3.y,
                             s0.z + s1.z + s2.z + s3.z, s0.w + s1.w + s2.w + s3.w);
      *reinterpret_cast<float4*>(&ps[i]) = r;
    }
    if (tid < CC) outcnts[slot * CC + tid] = lcnt[tid];
  } else {     // PATH B: atomic accumulate into per-batch sums
    float* __restrict__ gs = outsums + (size_t)b * CC * DD;
    for (int i = tid; i < CC * DD; i += 256) {
      float s = lsum[0][i] + lsum[1][i] + lsum[2][i] + lsum[3][i];
      atomicAdd(&gs[i], s);
    }
    if (tid < CC) atomicAdd(&outcnts[b * CC + tid], lcnt[tid]);
  }
}

// ---------------- Kernel A2: fold 32 chunk-partials per batch ---------------
__global__ __launch_bounds__(256) void reduce_partials_kernel(
    const float* __restrict__ psums, const float* __restrict__ pcnts,
    float* __restrict__ rsums, float* __restrict__ rcnts) {
  const int j = blockIdx.x;          // 256 blocks: 16 per batch
  const int b = j >> 4;
  const int e0 = (j & 15) * 256;
  const int tid = threadIdx.x;
  float s = 0.f;
#pragma unroll 8
  for (int c = 0; c < CHUNKS; ++c)
    s += psums[((size_t)(b * CHUNKS + c)) * CC * DD + e0 + tid];
  rsums[(size_t)b * CC * DD + e0 + tid] = s;
  if ((j & 15) == 0 && tid < CC) {
    float cs = 0.f;
#pragma unroll 8
    for (int c = 0; c < CHUNKS; ++c) cs += pcnts[(b * CHUNKS + c) * CC + tid];
    rcnts[b * CC + tid] = cs;
  }
}

// ---------------- Kernel 3: means -> gram -> triu -> per-batch loss ---------
#define MSTR 132
__global__ __launch_bounds__(512) void finish_kernel(
    const float* __restrict__ gsums, const float* __restrict__ gcounts,
    float* __restrict__ lossp, float* __restrict__ out, int mode) {
  __shared__ float mean[CC * MSTR];
  __shared__ float cnt[CC];
  __shared__ float red[512];

  const int b = blockIdx.x;
  const int tid = threadIdx.x;

  if (tid < CC) cnt[tid] = gcounts[b * CC + tid];
  __syncthreads();

  for (int i = tid; i < CC * DD; i += 512) {
    int c = i >> 7;
    int d = i & 127;
    mean[c * MSTR + d] = gsums[(size_t)b * CC * DD + i] / fmaxf(cnt[c], 1.f);
  }
  __syncthreads();

  float acc = 0.f;
  if (tid < (CC * (CC - 1)) / 2) {
    int c = 0, rem = tid;
    while (rem >= (CC - 1 - c)) { rem -= (CC - 1 - c); ++c; }
    int e = c + 1 + rem;
    const float4* mc = reinterpret_cast<const float4*>(&mean[c * MSTR]);
    const float4* me = reinterpret_cast<const float4*>(&mean[e * MSTR]);
    float dot = 0.f;
#pragma unroll 8
    for (int j = 0; j < DD / 4; ++j) {
      float4 a = mc[j], bb = me[j];
      dot += a.x * bb.x + a.y * bb.y + a.z * bb.z + a.w * bb.w;
    }
    acc = fabsf(dot);
  }

  red[tid] = acc;
  __syncthreads();
  for (int s = 256; s > 0; s >>= 1) {
    if (tid < s) red[tid] += red[tid + s];
    __syncthreads();
  }

  if (tid == 0) {
    float valid = 0.f;
    for (int c = 0; c < CC; ++c) valid += (cnt[c] > 0.f) ? 1.f : 0.f;
    float denom = (valid > 1.f) ? valid * (valid - 1.f) * 0.5f : 1.f;
    float v = red[0] / denom * (1.0f / BB);
    if (mode) lossp[b] = v;
    else atomicAdd(out, v);
  }
}

// ---------------- Kernel A4: final mean -> d_out ----------------------------
__global__ __launch_bounds__(64) void final_kernel(
    const float* __restrict__ lossp, float* __restrict__ out) {
  float v = (threadIdx.x < BB) ? lossp[threadIdx.x] : 0.f;
#pragma unroll
  for (int o = 8; o > 0; o >>= 1) v += __shfl_down(v, o, 16);
  if (threadIdx.x == 0) out[0] = v;
}

extern "C" void kernel_launch(void* const* d_in, const int* in_sizes, int n_in,
                              void* d_out, int out_size, void* d_ws, size_t ws_size,
                              hipStream_t stream) {
  const float* x   = (const float*)d_in[0];
  const int*   ids = (const int*)d_in[1];
  float* out = (float*)d_out;
  float* ws  = (float*)d_ws;

  dim3 grid1(CHUNKS, BB);
  if (ws_size >= WS_A_FLOATS * sizeof(float)) {
    // PATH A: no memsets, no global atomics — fully deterministic stores.
    float* psums = ws + P_SUMS;
    float* pcnts = ws + P_CNTS;
    float* rsums = ws + R_SUMS;
    float* rcnts = ws + R_CNTS;
    float* lossp = ws + LOSSP;
    seg_sum_kernel<<<grid1, 256, 0, stream>>>(x, ids, psums, pcnts, 1);
    reduce_partials_kernel<<<256, 256, 0, stream>>>(psums, pcnts, rsums, rcnts);
    finish_kernel<<<BB, 512, 0, stream>>>(rsums, rcnts, lossp, out, 1);
    final_kernel<<<1, 64, 0, stream>>>(lossp, out);
  } else {
    // PATH B: atomic accumulate (needs zeroed accumulators + out).
    float* gsums   = ws;
    float* gcounts = gsums + (size_t)BB * CC * DD;
    const size_t wsb = ((size_t)BB * CC * DD + (size_t)BB * CC) * sizeof(float);
    hipMemsetAsync(d_ws, 0, wsb, stream);
    hipMemsetAsync(d_out, 0, sizeof(float), stream);
    seg_sum_kernel<<<grid1, 256, 0, stream>>>(x, ids, gsums, gcounts, 0);
    finish_kernel<<<BB, 512, 0, stream>>>(gsums, gcounts, nullptr, out, 0);
  }
}

// Round 7
// 39.159 us; speedup vs baseline: 4.9331x; 1.0443x over previous
//
#include <hip/hip_runtime.h>
#include <hip/hip_bf16.h>

#define BB 16
#define NN 16384
#define DD 128
#define CC 32
#define CHUNKS 32
#define NBLK (BB * CHUNKS)                  // 512
#define ROWS_PER_BLOCK (NN / CHUNKS)        // 512
#define ROWS_PER_WAVE  (ROWS_PER_BLOCK / 4) // 128

// ---- PATH A workspace layout (floats) ----
#define P_SUMS 0                                   // NBLK*4096
#define P_CNTS ((size_t)NBLK * CC * DD)            // NBLK*32
#define LOSSP  (P_CNTS + (size_t)NBLK * CC)        // BB
#define CTR    (LOSSP + BB)                        // 1 (int)
#define WS_A_FLOATS (CTR + 1)

// ---------------- Kernel 1: segment sums + counts (branchless LDS RMW) ------
// 512 blocks, 4 waves; per-wave private 16 KB slab; lane l owns d={2l,2l+1}.
// Hot loop: plain ds_read_b64 + 2 adds + ds_write_b64; 16 loads in flight.
__global__ __launch_bounds__(256) void seg_sum_kernel(
    const float* __restrict__ x, const int* __restrict__ ids,
    float* __restrict__ outsums, float* __restrict__ outcnts,
    int* __restrict__ counter, int mode) {
  __shared__ float lsum[4][CC * DD];      // 64 KB
  __shared__ float lcnt[CC];
  __shared__ int   lcid[ROWS_PER_BLOCK];  // 2 KB

  const int tid  = threadIdx.x;
  const int b    = blockIdx.y;
  const int row0 = blockIdx.x * ROWS_PER_BLOCK;
  const int lane = tid & 63;
  const int w    = tid >> 6;
  const int slot = b * CHUNKS + blockIdx.x;
  const int* __restrict__ idrow = ids + (size_t)b * NN;

  if (tid < CC) lcnt[tid] = 0.f;
  lcid[tid]       = idrow[row0 + tid];
  lcid[tid + 256] = idrow[row0 + tid + 256];
  {
    const float4 z4 = make_float4(0.f, 0.f, 0.f, 0.f);
#pragma unroll
    for (int i = 0; i < 16; ++i)
      *reinterpret_cast<float4*>(&lsum[w][(i * 64 + lane) * 4]) = z4;
  }
  __syncthreads();
  atomicAdd(&lcnt[lcid[tid]], 1.f);
  atomicAdd(&lcnt[lcid[tid + 256]], 1.f);

  const float2* __restrict__ x2 =
      reinterpret_cast<const float2*>(x + (size_t)b * NN * DD);
  const int wbase = w * ROWS_PER_WAVE;
  float* const slab = &lsum[w][0];

  float2 vA[16], vB[16];
  int cA[16], cB[16];

#define LOADG(V, C, g)                                                     \
  {                                                                        \
    _Pragma("unroll") for (int k = 0; k < 16; ++k) {                       \
      const int rl = wbase + (g) * 16 + k;                                 \
      V[k] = x2[(size_t)(row0 + rl) * 64 + lane];                          \
      C[k] = lcid[rl];                                                     \
    }                                                                      \
  }
#define RMWG(V, C)                                                         \
  {                                                                        \
    _Pragma("unroll") for (int k = 0; k < 16; ++k) {                       \
      float2* p = reinterpret_cast<float2*>(&slab[C[k] * DD + 2 * lane]);  \
      float2 old = *p;                                                     \
      *p = make_float2(old.x + V[k].x, old.y + V[k].y);                    \
    }                                                                      \
  }

  LOADG(vA, cA, 0)                         // 8 groups of 16 rows
#pragma unroll
  for (int i = 0; i < 3; ++i) {
    LOADG(vB, cB, 2 * i + 1)
    RMWG(vA, cA)
    LOADG(vA, cA, 2 * i + 2)
    RMWG(vB, cB)
  }
  LOADG(vB, cB, 7)
  RMWG(vA, cA)
  RMWG(vB, cB)
#undef LOADG
#undef RMWG
  __syncthreads();

  if (mode) {  // PATH A: fold 4 slabs, plain-store 16 KB partial to own slot
    float* __restrict__ ps = outsums + (size_t)slot * CC * DD;
#pragma unroll
    for (int it = 0; it < 4; ++it) {
      const int i = (it * 256 + tid) * 4;
      float4 s0 = *reinterpret_cast<const float4*>(&lsum[0][i]);
      float4 s1 = *reinterpret_cast<const float4*>(&lsum[1][i]);
      float4 s2 = *reinterpret_cast<const float4*>(&lsum[2][i]);
      float4 s3 = *reinterpret_cast<const float4*>(&lsum[3][i]);
      float4 r = make_float4(s0.x + s1.x + s2.x + s3.x, s0.y + s1.y + s2.y + s3.y,
                             s0.z + s1.z + s2.z + s3.z, s0.w + s1.w + s2.w + s3.w);
      *reinterpret_cast<float4*>(&ps[i]) = r;
    }
    if (tid < CC) outcnts[slot * CC + tid] = lcnt[tid];
    if (slot == 0 && tid == 0)
      __hip_atomic_store(counter, 0, __ATOMIC_RELAXED, __HIP_MEMORY_SCOPE_AGENT);
  } else {     // PATH B: atomic accumulate into per-batch sums
    float* __restrict__ gs = outsums + (size_t)b * CC * DD;
    for (int i = tid; i < CC * DD; i += 256) {
      float s = lsum[0][i] + lsum[1][i] + lsum[2][i] + lsum[3][i];
      atomicAdd(&gs[i], s);
    }
    if (tid < CC) atomicAdd(&outcnts[b * CC + tid], lcnt[tid]);
  }
}

// ---------------- Kernel 2 (PATH A): fused reduce + gram + final ------------
// 16 blocks x 512 thr. Block b: reg-reduce 32 partial slabs (thread t owns
// elements [t*8, t*8+8)), means -> LDS, 496 pair-dots, publish lossp[b],
// last block (agent-scope counter) sums slots in fixed order -> out.
#define MSTR 132
__global__ __launch_bounds__(512) void finish_fused_kernel(
    const float* __restrict__ psums, const float* __restrict__ pcnts,
    float* __restrict__ lossp, int* __restrict__ counter,
    float* __restrict__ out) {
  __shared__ float mean[CC * MSTR];
  __shared__ float cnt[CC];
  __shared__ float red[512];

  const int b = blockIdx.x;
  const int tid = threadIdx.x;

  if (tid < CC) {
    float cs = 0.f;
#pragma unroll 8
    for (int c = 0; c < CHUNKS; ++c) cs += pcnts[(b * CHUNKS + c) * CC + tid];
    cnt[tid] = cs;
  }

  // register-reduce: 2 float4 per thread across 32 slabs (coalesced)
  float4 a0 = make_float4(0.f, 0.f, 0.f, 0.f), a1 = a0;
  const size_t base = (size_t)b * CHUNKS * CC * DD + (size_t)tid * 8;
#pragma unroll 4
  for (int c = 0; c < CHUNKS; ++c) {
    const float4* p = reinterpret_cast<const float4*>(&psums[base + (size_t)c * CC * DD]);
    float4 q0 = p[0], q1 = p[1];
    a0.x += q0.x; a0.y += q0.y; a0.z += q0.z; a0.w += q0.w;
    a1.x += q1.x; a1.y += q1.y; a1.z += q1.z; a1.w += q1.w;
  }
  __syncthreads();  // cnt ready

  {
    const int c = tid >> 4;                 // (tid*8)>>7
    const int d0 = (tid & 15) * 8;
    const float inv = 1.f / fmaxf(cnt[c], 1.f);
    float* mrow = &mean[c * MSTR + d0];
    mrow[0] = a0.x * inv; mrow[1] = a0.y * inv; mrow[2] = a0.z * inv; mrow[3] = a0.w * inv;
    mrow[4] = a1.x * inv; mrow[5] = a1.y * inv; mrow[6] = a1.z * inv; mrow[7] = a1.w * inv;
  }
  __syncthreads();

  float acc = 0.f;
  if (tid < (CC * (CC - 1)) / 2) {
    int c = 0, rem = tid;
    while (rem >= (CC - 1 - c)) { rem -= (CC - 1 - c); ++c; }
    int e = c + 1 + rem;
    const float4* mc = reinterpret_cast<const float4*>(&mean[c * MSTR]);
    const float4* me = reinterpret_cast<const float4*>(&mean[e * MSTR]);
    float dot = 0.f;
#pragma unroll 8
    for (int j = 0; j < DD / 4; ++j) {
      float4 u = mc[j], v = me[j];
      dot += u.x * v.x + u.y * v.y + u.z * v.z + u.w * v.w;
    }
    acc = fabsf(dot);
  }

  red[tid] = acc;
  __syncthreads();
  for (int s = 256; s > 0; s >>= 1) {
    if (tid < s) red[tid] += red[tid + s];
    __syncthreads();
  }

  if (tid == 0) {
    float valid = 0.f;
    for (int c = 0; c < CC; ++c) valid += (cnt[c] > 0.f) ? 1.f : 0.f;
    float denom = (valid > 1.f) ? valid * (valid - 1.f) * 0.5f : 1.f;
    float v = red[0] / denom * (1.0f / BB);
    __hip_atomic_store(&lossp[b], v, __ATOMIC_RELAXED, __HIP_MEMORY_SCOPE_AGENT);
    __threadfence();
    int old = __hip_atomic_fetch_add(counter, 1, __ATOMIC_ACQ_REL,
                                     __HIP_MEMORY_SCOPE_AGENT);
    if (old == BB - 1) {  // last block: fixed-order sum -> deterministic
      float s = 0.f;
#pragma unroll
      for (int i = 0; i < BB; ++i)
        s += __hip_atomic_load(&lossp[i], __ATOMIC_RELAXED,
                               __HIP_MEMORY_SCOPE_AGENT);
      out[0] = s;
    }
  }
}

// ---------------- PATH B finish (fallback) ----------------------------------
__global__ __launch_bounds__(512) void finish_kernel_b(
    const float* __restrict__ gsums, const float* __restrict__ gcounts,
    float* __restrict__ out) {
  __shared__ float mean[CC * MSTR];
  __shared__ float cnt[CC];
  __shared__ float red[512];

  const int b = blockIdx.x;
  const int tid = threadIdx.x;

  if (tid < CC) cnt[tid] = gcounts[b * CC + tid];
  __syncthreads();

  for (int i = tid; i < CC * DD; i += 512) {
    int c = i >> 7;
    int d = i & 127;
    mean[c * MSTR + d] = gsums[(size_t)b * CC * DD + i] / fmaxf(cnt[c], 1.f);
  }
  __syncthreads();

  float acc = 0.f;
  if (tid < (CC * (CC - 1)) / 2) {
    int c = 0, rem = tid;
    while (rem >= (CC - 1 - c)) { rem -= (CC - 1 - c); ++c; }
    int e = c + 1 + rem;
    const float4* mc = reinterpret_cast<const float4*>(&mean[c * MSTR]);
    const float4* me = reinterpret_cast<const float4*>(&mean[e * MSTR]);
    float dot = 0.f;
#pragma unroll 8
    for (int j = 0; j < DD / 4; ++j) {
      float4 u = mc[j], v = me[j];
      dot += u.x * v.x + u.y * v.y + u.z * v.z + u.w * v.w;
    }
    acc = fabsf(dot);
  }

  red[tid] = acc;
  __syncthreads();
  for (int s = 256; s > 0; s >>= 1) {
    if (tid < s) red[tid] += red[tid + s];
    __syncthreads();
  }

  if (tid == 0) {
    float valid = 0.f;
    for (int c = 0; c < CC; ++c) valid += (cnt[c] > 0.f) ? 1.f : 0.f;
    float denom = (valid > 1.f) ? valid * (valid - 1.f) * 0.5f : 1.f;
    atomicAdd(out, red[0] / denom * (1.0f / BB));
  }
}

extern "C" void kernel_launch(void* const* d_in, const int* in_sizes, int n_in,
                              void* d_out, int out_size, void* d_ws, size_t ws_size,
                              hipStream_t stream) {
  const float* x   = (const float*)d_in[0];
  const int*   ids = (const int*)d_in[1];
  float* out = (float*)d_out;
  float* ws  = (float*)d_ws;

  dim3 grid1(CHUNKS, BB);
  if (ws_size >= WS_A_FLOATS * sizeof(float)) {
    // PATH A: 2 kernels, no memsets, no global float atomics.
    float* psums = ws + P_SUMS;
    float* pcnts = ws + P_CNTS;
    float* lossp = ws + LOSSP;
    int*   ctr   = (int*)(ws + CTR);
    seg_sum_kernel<<<grid1, 256, 0, stream>>>(x, ids, psums, pcnts, ctr, 1);
    finish_fused_kernel<<<BB, 512, 0, stream>>>(psums, pcnts, lossp, ctr, out);
  } else {
    // PATH B: atomic accumulate (needs zeroed accumulators + out).
    float* gsums   = ws;
    float* gcounts = gsums + (size_t)BB * CC * DD;
    const size_t wsb = ((size_t)BB * CC * DD + (size_t)BB * CC) * sizeof(float);
    hipMemsetAsync(d_ws, 0, wsb, stream);
    hipMemsetAsync(d_out, 0, sizeof(float), stream);
    seg_sum_kernel<<<grid1, 256, 0, stream>>>(x, ids, gsums, gcounts, nullptr, 0);
    finish_kernel_b<<<BB, 512, 0, stream>>>(gsums, gcounts, out);
  }
}